// Round 15
// baseline (76996.875 us; speedup 1.0000x reference)
//
#include <hip/hip_runtime.h>
#include <hip/hip_fp16.h>

#define NWG 64    // persistent workgroups; each owns 16 hidden units
#define NTH 1024  // 16 waves; wave j owns unit u0+j end-to-end
#define T1  8192  // S*W word steps
#define SS  64
#define WW  128

typedef unsigned long long u64;
typedef unsigned int u32x4 __attribute__((ext_vector_type(4)));

// ws layout (8B units):
// [0..1023]       hbuf64: 2 slots x 512 u64, each = [tag:32 | half2(h[2u],h[2u+1])]
// [1024..66559]   encs64: 64 x 1024 fp32-tagged (written/read once)
// [66560..66623]  part64: 64 tagged partials
// memset 0 each call (tag 0 == invalid; valid tags start at 1).
// Protocol (R12-proven, byte-identical): agent-scope swap publish (pair-packed,
// lane-adjacent from ONE wave instr -> coalesced), sc1 serial spin, fp32 encs.
// R15 change: 64 WGs (readers halved), 16 waves/WG, fp16 wih in LDS (128KB).

__device__ __forceinline__ u64 aload(const u64* p) {
  return __hip_atomic_load(p, __ATOMIC_RELAXED, __HIP_MEMORY_SCOPE_AGENT);
}
__device__ __forceinline__ void aswap(u64* p, u64 v) {
  (void)__hip_atomic_exchange(p, v, __ATOMIC_RELAXED, __HIP_MEMORY_SCOPE_AGENT);
}
__device__ __forceinline__ u64 packf(float v, unsigned tag) {
  return ((u64)tag << 32) | (u64)__float_as_uint(v);
}
__device__ __forceinline__ unsigned pk2(float a, float b) {
  __half2 h = __floats2half2_rn(a, b);
  return *(unsigned*)&h;
}
__device__ __forceinline__ float2 upk2(unsigned u) {
  __half2 h = *(__half2*)&u;
  return __half22float2(h);
}
// fast tanh via exp pipe: tanh(x) = 1 - 2/(1+e^{2x})
__device__ __forceinline__ float ftanh(float x) {
  return 1.f - 2.f / (1.f + __expf(2.f * x));
}

// one 16B agent-scope load (sc1: bypass XCD L2, LLC-served; R8 operand order)
__device__ __forceinline__ u32x4 load16_sc1(const void* p) {
  u32x4 r;
  asm volatile("global_load_dwordx4 %0, %1, off sc1\n\ts_waitcnt vmcnt(0)"
               : "=&v"(r) : "v"(p) : "memory");
  return r;
}

__global__ __launch_bounds__(NTH) __attribute__((amdgpu_waves_per_eu(4, 4)))
void lstm_hier_attn(const float* __restrict__ xin,
                    const float* __restrict__ h1_0, const float* __restrict__ c1_0,
                    const float* __restrict__ h2_0, const float* __restrict__ c2_0,
                    const float* __restrict__ Wih1, const float* __restrict__ Whh1,
                    const float* __restrict__ bih1, const float* __restrict__ bhh1,
                    const float* __restrict__ Wih2, const float* __restrict__ Whh2,
                    const float* __restrict__ bih2, const float* __restrict__ bhh2,
                    const float* __restrict__ attw, const float* __restrict__ atts,
                    const float* __restrict__ Wf,   const float* __restrict__ bfb,
                    u64* hbuf64, u64* encs64, u64* part64, float* out)
{
  const int wid = blockIdx.x;
  const int tid = threadIdx.x;
  const int wv  = tid >> 6;   // wave id 0..15 == owned unit index
  const int l   = tid & 63;
  const int u0  = wid << 4;   // first of 16 owned hidden units

  __shared__ __half wih_lds[64 * 1024];  // 128KB fp16 x-weights (64 gate rows)
  __shared__ float h_lds[2][1024];
  __shared__ float e_lds[2][1024];
  __shared__ float aw_lds[WW];
  __shared__ float as_lds[SS];
  __shared__ float h_out[16];
  __shared__ float fin_lds[16];

  if (tid == 0) {   // one-time softmaxes
    float m = -1e30f;
    for (int i = 0; i < WW; ++i) m = fmaxf(m, attw[i]);
    float ssum = 0.f;
    for (int i = 0; i < WW; ++i) { float e = __expf(attw[i] - m); aw_lds[i] = e; ssum += e; }
    float inv = 1.f / ssum;
    for (int i = 0; i < WW; ++i) aw_lds[i] *= inv;
    m = -1e30f;
    for (int i = 0; i < SS; ++i) m = fmaxf(m, atts[i]);
    ssum = 0.f;
    for (int i = 0; i < SS; ++i) { float e = __expf(atts[i] - m); as_lds[i] = e; ssum += e; }
    inv = 1.f / ssum;
    for (int i = 0; i < SS; ++i) as_lds[i] *= inv;
  }

  // wih1 -> fp16 LDS. local row rr = gate*16 + unit_local; global = gate*1024+u0+j
  for (int q = 0; q < 64; ++q) {
    const int idx = (q << 10) + tid;       // 0..65535
    const int rr = idx >> 10, col = idx & 1023;
    wih_lds[idx] = __float2half_rn(
        Wih1[(size_t)(((rr >> 4) << 10) + u0 + (rr & 15)) * 1024 + col]);
  }
  // whh1 -> registers: wave wv, 4 gate rows of unit u0+wv, cols l+64m
  float whh[4][16], bias[4];
#pragma unroll
  for (int g = 0; g < 4; ++g) {
    const int grow = (g << 10) + u0 + wv;
    bias[g] = bih1[grow] + bhh1[grow];
    const float* ph = Whh1 + (size_t)grow * 1024 + l;
#pragma unroll
    for (int m = 0; m < 16; ++m) whh[g][m] = ph[m << 6];
  }
#pragma unroll
  for (int g = 0; g < 4; ++g)
#pragma unroll
    for (int m = 0; m < 16; ++m) asm volatile("" : "+v"(whh[g][m]));

  float c   = c1_0[u0 + wv];   // unit state (uniform across the wave)
  float enc = 0.f, row = 0.f;
  const int rb0 = (0 * 16 + wv) << 10, rb1 = (1 * 16 + wv) << 10,
            rb2 = (2 * 16 + wv) << 10, rb3 = (3 * 16 + wv) << 10;
  __syncthreads();

  // ======================= layer 1: 8192 word steps =======================
  for (int k = 0; k < T1; ++k) {
    const int p = k & 1;
    // x-partial (pre-spin, off critical path)
    const float* xrow = xin + (size_t)k * 1024;
    float a0 = 0.f, a1 = 0.f, a2 = 0.f, a3 = 0.f;
#pragma unroll
    for (int m = 0; m < 16; ++m) {
      const int cix = (m << 6) + l;
      const float x = xrow[cix];
      a0 += __half2float(wih_lds[rb0 + cix]) * x;
      a1 += __half2float(wih_lds[rb1 + cix]) * x;
      a2 += __half2float(wih_lds[rb2 + cix]) * x;
      a3 += __half2float(wih_lds[rb3 + cix]) * x;
    }

    if (k > 0) {
      if (tid < 256) {   // serial spin (R12-proven): one 16B load covers 4 h
        const u64* q = hbuf64 + ((size_t)p << 9) + (tid << 1);
        const unsigned t = (unsigned)k;
        u32x4 r;
        for (;;) { r = load16_sc1(q);
          if (__builtin_expect(r.y == t && r.w == t, 1)) break; }
        const float2 ha = upk2(r.x), hb = upk2(r.z);
        float* d = h_lds[p] + (tid << 2);
        d[0] = ha.x; d[1] = ha.y; d[2] = hb.x; d[3] = hb.y;
      }
    } else if (tid < 512) {
      h_lds[0][(tid << 1) + 0] = h1_0[(tid << 1) + 0];
      h_lds[0][(tid << 1) + 1] = h1_0[(tid << 1) + 1];
    }
    __syncthreads();   // B1: h_lds[p] ready

#pragma unroll
    for (int m = 0; m < 16; ++m) {
      const float hv = h_lds[p][(m << 6) + l];
      a0 += whh[0][m] * hv; a1 += whh[1][m] * hv;
      a2 += whh[2][m] * hv; a3 += whh[3][m] * hv;
    }
#pragma unroll
    for (int mm = 1; mm < 64; mm <<= 1) {
      a0 += __shfl_xor(a0, mm); a1 += __shfl_xor(a1, mm);
      a2 += __shfl_xor(a2, mm); a3 += __shfl_xor(a3, mm);
    }
    const float ig = a0 + bias[0], fg = a1 + bias[1];
    const float gg = a2 + bias[2], og = a3 + bias[3];
    const float si = 1.f / (1.f + __expf(-ig));
    const float sf = 1.f / (1.f + __expf(-fg));
    const float so = 1.f / (1.f + __expf(-og));
    c = sf * c + si * ftanh(gg);
    const float h = so * ftanh(c);
    if (l == 0) h_out[wv] = h;
    __syncthreads();   // B2: h_out ready for pair-packing
    if (tid < 8)       // 8 LANE-ADJACENT swaps in ONE wave instr (64B) -> coalesced
      aswap(&hbuf64[((size_t)((k + 1) & 1) << 9) + (wid << 3) + tid],
            ((u64)(unsigned)(k + 1) << 32) |
            (u64)pk2(h_out[(tid << 1)], h_out[(tid << 1) + 1]));
    const int wd = k & (WW - 1);
    const float e_new = enc + aw_lds[wd] * h;        // enc = aw @ hs (online)
    if (wd == WW - 1) {
      if (l == 0)
        aswap(&encs64[((size_t)(k >> 7) << 10) + u0 + wv],
              packf(e_new, (unsigned)((k >> 7) + 1)));
      enc = 0.f;
    } else enc = e_new;
  }

  // ======================= layer 2: 64 sentence steps =======================
  __syncthreads();   // all wih1 reads done before overwrite
  for (int q = 0; q < 64; ++q) {
    const int idx = (q << 10) + tid;
    const int rr = idx >> 10, col = idx & 1023;
    wih_lds[idx] = __float2half_rn(
        Wih2[(size_t)(((rr >> 4) << 10) + u0 + (rr & 15)) * 1024 + col]);
  }
#pragma unroll
  for (int g = 0; g < 4; ++g) {
    const int grow = (g << 10) + u0 + wv;
    bias[g] = bih2[grow] + bhh2[grow];
    const float* ph = Whh2 + (size_t)grow * 1024 + l;
#pragma unroll
    for (int m = 0; m < 16; ++m) whh[g][m] = ph[m << 6];
  }
#pragma unroll
  for (int g = 0; g < 4; ++g)
#pragma unroll
    for (int m = 0; m < 16; ++m) asm volatile("" : "+v"(whh[g][m]));
  c = c2_0[u0 + wv];

  for (int s2 = 0; s2 < SS; ++s2) {
    const unsigned kg = (unsigned)(T1 + s2);
    const int p = (int)(kg & 1), pe = s2 & 1;
    if (tid < 512) {  // enc row: fp32-tagged pairs; tags ancient -> first try
      const u64* q = encs64 + ((size_t)s2 << 10) + (tid << 1);
      const unsigned t = (unsigned)(s2 + 1);
      u32x4 r;
      for (;;) { r = load16_sc1(q);
        if (__builtin_expect(r.y == t && r.w == t, 1)) break; }
      e_lds[pe][(tid << 1) + 0] = __uint_as_float(r.x);
      e_lds[pe][(tid << 1) + 1] = __uint_as_float(r.z);
    }
    // h gate; s2==0 spins for tag 8192 (boundary), then overrides with h2_0
    if (tid < 256) {
      const u64* q = hbuf64 + ((size_t)p << 9) + (tid << 1);
      u32x4 r;
      for (;;) { r = load16_sc1(q);
        if (__builtin_expect(r.y == kg && r.w == kg, 1)) break; }
      const float2 ha = upk2(r.x), hb = upk2(r.z);
      float* d = h_lds[p] + (tid << 2);
      d[0] = ha.x; d[1] = ha.y; d[2] = hb.x; d[3] = hb.y;
    }
    if (s2 == 0 && tid < 512) {
      h_lds[0][(tid << 1) + 0] = h2_0[(tid << 1) + 0];
      h_lds[0][(tid << 1) + 1] = h2_0[(tid << 1) + 1];
    }
    __syncthreads();   // B1

    float a0 = 0.f, a1 = 0.f, a2 = 0.f, a3 = 0.f;
#pragma unroll
    for (int m = 0; m < 16; ++m) {
      const int cix = (m << 6) + l;
      const float ev = e_lds[pe][cix];
      a0 += __half2float(wih_lds[rb0 + cix]) * ev;
      a1 += __half2float(wih_lds[rb1 + cix]) * ev;
      a2 += __half2float(wih_lds[rb2 + cix]) * ev;
      a3 += __half2float(wih_lds[rb3 + cix]) * ev;
      const float hv = h_lds[p][cix];
      a0 += whh[0][m] * hv; a1 += whh[1][m] * hv;
      a2 += whh[2][m] * hv; a3 += whh[3][m] * hv;
    }
#pragma unroll
    for (int mm = 1; mm < 64; mm <<= 1) {
      a0 += __shfl_xor(a0, mm); a1 += __shfl_xor(a1, mm);
      a2 += __shfl_xor(a2, mm); a3 += __shfl_xor(a3, mm);
    }
    const float ig = a0 + bias[0], fg = a1 + bias[1];
    const float gg = a2 + bias[2], og = a3 + bias[3];
    const float si = 1.f / (1.f + __expf(-ig));
    const float sf = 1.f / (1.f + __expf(-fg));
    const float so = 1.f / (1.f + __expf(-og));
    c = sf * c + si * ftanh(gg);
    const float h = so * ftanh(c);
    if (l == 0) h_out[wv] = h;
    __syncthreads();   // B2
    if (tid < 8)
      aswap(&hbuf64[((size_t)((kg + 1) & 1) << 9) + (wid << 3) + tid],
            ((u64)(kg + 1u) << 32) |
            (u64)pk2(h_out[(tid << 1)], h_out[(tid << 1) + 1]));
    row += as_lds[s2] * h;                           // row = asn @ hs2 (online)
  }

  // =================== final projection + sigmoid ===================
  if (l == 0) fin_lds[wv] = row * Wf[u0 + wv];
  __syncthreads();
  if (tid == 0) {
    float pp = 0.f;
#pragma unroll
    for (int j = 0; j < 16; ++j) pp += fin_lds[j];
    aswap(&part64[wid], packf(pp, 1u));
  }
  if (wid == 0) {
    if (tid < NWG) {
      u64 a;
      for (;;) { a = aload(&part64[tid]); if ((unsigned)(a >> 32) == 1u) break; }
      e_lds[0][tid] = __uint_as_float((unsigned)a);
    }
    __syncthreads();
    if (wv == 0) {
      float pp = e_lds[0][l];
#pragma unroll
      for (int mm = 1; mm < 64; mm <<= 1) pp += __shfl_xor(pp, mm);
      if (l == 0) out[0] = 1.f / (1.f + __expf(-(pp + bfb[0])));
    }
  }
}

extern "C" void kernel_launch(void* const* d_in, const int* in_sizes, int n_in,
                              void* d_out, int out_size, void* d_ws, size_t ws_size,
                              hipStream_t stream) {
  (void)in_sizes; (void)n_in; (void)out_size; (void)ws_size;
  const float* xin  = (const float*)d_in[0];
  const float* h1   = (const float*)d_in[1];
  const float* c1   = (const float*)d_in[2];
  const float* h2   = (const float*)d_in[3];
  const float* c2   = (const float*)d_in[4];
  const float* Wih1 = (const float*)d_in[5];
  const float* Whh1 = (const float*)d_in[6];
  const float* bih1 = (const float*)d_in[7];
  const float* bhh1 = (const float*)d_in[8];
  const float* Wih2 = (const float*)d_in[9];
  const float* Whh2 = (const float*)d_in[10];
  const float* bih2 = (const float*)d_in[11];
  const float* bhh2 = (const float*)d_in[12];
  const float* attw = (const float*)d_in[13];
  const float* atts = (const float*)d_in[14];
  const float* Wf   = (const float*)d_in[15];
  const float* bfb  = (const float*)d_in[16];

  u64* hbuf64 = (u64*)d_ws;                 // 1024 u64 (2 x 512, fp16-packed)
  u64* encs64 = hbuf64 + 1024;              // 65536 u64
  u64* part64 = encs64 + 65536;             // 64 u64
  float* out  = (float*)d_out;

  // tags must start invalid (0) every call — replay-safe, graph-capture legal
  hipMemsetAsync(d_ws, 0, (1024 + 65536 + 64) * sizeof(u64), stream);
  lstm_hier_attn<<<dim3(NWG), dim3(NTH), 0, stream>>>(
      xin, h1, c1, h2, c2, Wih1, Whh1, bih1, bhh1,
      Wih2, Whh2, bih2, bhh2, attw, atts, Wf, bfb,
      hbuf64, encs64, part64, out);
}

// Round 16
// 15370.662 us; speedup vs baseline: 5.0093x; 5.0093x over previous
//
#include <hip/hip_runtime.h>
#include <hip/hip_fp16.h>

#define NWG 128   // persistent workgroups; each owns 8 hidden units
#define NTH 512   // 8 waves; wave j owns unit u0+j end-to-end
#define T1  8192  // S*W word steps
#define SS  64
#define WW  128

typedef unsigned long long u64;
typedef unsigned int u32x4 __attribute__((ext_vector_type(4)));

// ws layout (8B units):
// [0..1023]       hbuf64: 2 slots x 512 u64, each = [tag:32 | half2(h[2u],h[2u+1])]
// [1024..66559]   encs64: 64 x 1024 fp32-tagged (written/read once)
// [66560..66687]  part64: 128 tagged partials
// memset 0 each call (tag 0 == invalid; valid tags start at 1).
// Protocol: agent-scope only. Publish = atomic swap (R11: keeps line LLC-
// resident), 4 lane-adjacent swaps in ONE wave instr (R13: coalescing is a
// wave-level property). Gather: 128 WGs x 4KB fp16 mailbox. This is the
// session Pareto point (R12: 15.97ms); R13/R14/R15 perturbations all regressed.

__device__ __forceinline__ u64 aload(const u64* p) {
  return __hip_atomic_load(p, __ATOMIC_RELAXED, __HIP_MEMORY_SCOPE_AGENT);
}
__device__ __forceinline__ void aswap(u64* p, u64 v) {
  (void)__hip_atomic_exchange(p, v, __ATOMIC_RELAXED, __HIP_MEMORY_SCOPE_AGENT);
}
__device__ __forceinline__ u64 packf(float v, unsigned tag) {
  return ((u64)tag << 32) | (u64)__float_as_uint(v);
}
__device__ __forceinline__ unsigned pk2(float a, float b) {
  __half2 h = __floats2half2_rn(a, b);
  return *(unsigned*)&h;
}
__device__ __forceinline__ float2 upk2(unsigned u) {
  __half2 h = *(__half2*)&u;
  return __half22float2(h);
}
// fast tanh via exp pipe: tanh(x) = 1 - 2/(1+e^{2x})
__device__ __forceinline__ float ftanh(float x) {
  return 1.f - 2.f / (1.f + __expf(2.f * x));
}

// one 16B agent-scope load (sc1: bypass XCD L2, LLC-served; R8 operand order)
__device__ __forceinline__ u32x4 load16_sc1(const void* p) {
  u32x4 r;
  asm volatile("global_load_dwordx4 %0, %1, off sc1\n\ts_waitcnt vmcnt(0)"
               : "=&v"(r) : "v"(p) : "memory");
  return r;
}

__global__ __launch_bounds__(NTH) __attribute__((amdgpu_waves_per_eu(2, 2)))
void lstm_hier_attn(const float* __restrict__ xin,
                    const float* __restrict__ h1_0, const float* __restrict__ c1_0,
                    const float* __restrict__ h2_0, const float* __restrict__ c2_0,
                    const float* __restrict__ Wih1, const float* __restrict__ Whh1,
                    const float* __restrict__ bih1, const float* __restrict__ bhh1,
                    const float* __restrict__ Wih2, const float* __restrict__ Whh2,
                    const float* __restrict__ bih2, const float* __restrict__ bhh2,
                    const float* __restrict__ attw, const float* __restrict__ atts,
                    const float* __restrict__ Wf,   const float* __restrict__ bfb,
                    u64* hbuf64, u64* encs64, u64* part64, float* out)
{
  const int wid = blockIdx.x;
  const int tid = threadIdx.x;
  const int wv  = tid >> 6;   // wave id 0..7 == owned unit index
  const int l   = tid & 63;
  const int u0  = wid << 3;   // first of 8 owned hidden units

  __shared__ float wih_lds[32 * 1024];   // 128KB x-weights (32 gate rows)
  __shared__ float h_lds[2][1024];
  __shared__ float e_lds[2][1024];
  __shared__ float aw_lds[WW];
  __shared__ float as_lds[SS];
  __shared__ float h_out[8];
  __shared__ float fin_lds[8];

  if (tid == 0) {   // one-time softmaxes
    float m = -1e30f;
    for (int i = 0; i < WW; ++i) m = fmaxf(m, attw[i]);
    float ssum = 0.f;
    for (int i = 0; i < WW; ++i) { float e = __expf(attw[i] - m); aw_lds[i] = e; ssum += e; }
    float inv = 1.f / ssum;
    for (int i = 0; i < WW; ++i) aw_lds[i] *= inv;
    m = -1e30f;
    for (int i = 0; i < SS; ++i) m = fmaxf(m, atts[i]);
    ssum = 0.f;
    for (int i = 0; i < SS; ++i) { float e = __expf(atts[i] - m); as_lds[i] = e; ssum += e; }
    inv = 1.f / ssum;
    for (int i = 0; i < SS; ++i) as_lds[i] *= inv;
  }

  // wih1 -> LDS. local row rr = gate*8 + unit_local; global = gate*1024+u0+j
  for (int q = 0; q < 64; ++q) {
    const int idx = (q << 9) + tid;        // 0..32767
    const int rr = idx >> 10, col = idx & 1023;
    wih_lds[idx] = Wih1[(size_t)(((rr >> 3) << 10) + u0 + (rr & 7)) * 1024 + col];
  }
  // whh1 -> registers: wave wv, 4 gate rows of unit u0+wv, cols l+64m
  float whh[4][16], bias[4];
#pragma unroll
  for (int g = 0; g < 4; ++g) {
    const int grow = (g << 10) + u0 + wv;
    bias[g] = bih1[grow] + bhh1[grow];
    const float* ph = Whh1 + (size_t)grow * 1024 + l;
#pragma unroll
    for (int m = 0; m < 16; ++m) whh[g][m] = ph[m << 6];
  }
#pragma unroll
  for (int g = 0; g < 4; ++g)
#pragma unroll
    for (int m = 0; m < 16; ++m) asm volatile("" : "+v"(whh[g][m]));

  float c   = c1_0[u0 + wv];   // unit state (uniform across the wave)
  float enc = 0.f, row = 0.f;
  const int rb0 = (0 * 8 + wv) << 10, rb1 = (1 * 8 + wv) << 10,
            rb2 = (2 * 8 + wv) << 10, rb3 = (3 * 8 + wv) << 10;
  __syncthreads();

  // ======================= layer 1: 8192 word steps =======================
  for (int k = 0; k < T1; ++k) {
    const int p = k & 1;
    // x-partial (pre-spin, off critical path)
    const float* xrow = xin + (size_t)k * 1024;
    float a0 = 0.f, a1 = 0.f, a2 = 0.f, a3 = 0.f;
#pragma unroll
    for (int m = 0; m < 16; ++m) {
      const int cix = (m << 6) + l;
      const float x = xrow[cix];
      a0 += wih_lds[rb0 + cix] * x; a1 += wih_lds[rb1 + cix] * x;
      a2 += wih_lds[rb2 + cix] * x; a3 += wih_lds[rb3 + cix] * x;
    }

    if (k > 0) {
      if (tid < 256) {   // threads 0..255: one 16B load covers 4 h (2 u64)
        const u64* q = hbuf64 + ((size_t)p << 9) + (tid << 1);
        const unsigned t = (unsigned)k;
        u32x4 r;
        for (;;) { r = load16_sc1(q);
          if (__builtin_expect(r.y == t && r.w == t, 1)) break; }
        const float2 ha = upk2(r.x), hb = upk2(r.z);
        float* d = h_lds[p] + (tid << 2);
        d[0] = ha.x; d[1] = ha.y; d[2] = hb.x; d[3] = hb.y;
      }
    } else {
      h_lds[0][(tid << 1) + 0] = h1_0[(tid << 1) + 0];
      h_lds[0][(tid << 1) + 1] = h1_0[(tid << 1) + 1];
    }
    __syncthreads();   // B1: h_lds[p] ready

#pragma unroll
    for (int m = 0; m < 16; ++m) {
      const float hv = h_lds[p][(m << 6) + l];
      a0 += whh[0][m] * hv; a1 += whh[1][m] * hv;
      a2 += whh[2][m] * hv; a3 += whh[3][m] * hv;
    }
#pragma unroll
    for (int mm = 1; mm < 64; mm <<= 1) {
      a0 += __shfl_xor(a0, mm); a1 += __shfl_xor(a1, mm);
      a2 += __shfl_xor(a2, mm); a3 += __shfl_xor(a3, mm);
    }
    const float ig = a0 + bias[0], fg = a1 + bias[1];
    const float gg = a2 + bias[2], og = a3 + bias[3];
    const float si = 1.f / (1.f + __expf(-ig));
    const float sf = 1.f / (1.f + __expf(-fg));
    const float so = 1.f / (1.f + __expf(-og));
    c = sf * c + si * ftanh(gg);
    const float h = so * ftanh(c);
    if (l == 0) h_out[wv] = h;
    __syncthreads();   // B2: h_out ready for pair-packing
    if (tid < 4)       // 4 LANE-ADJACENT swaps in ONE wave instr -> coalesced
      aswap(&hbuf64[((size_t)((k + 1) & 1) << 9) + (wid << 2) + tid],
            ((u64)(unsigned)(k + 1) << 32) |
            (u64)pk2(h_out[(tid << 1)], h_out[(tid << 1) + 1]));
    const int wd = k & (WW - 1);
    const float e_new = enc + aw_lds[wd] * h;        // enc = aw @ hs (online)
    if (wd == WW - 1) {
      if (l == 0)
        aswap(&encs64[((size_t)(k >> 7) << 10) + u0 + wv],
              packf(e_new, (unsigned)((k >> 7) + 1)));
      enc = 0.f;
    } else enc = e_new;
  }

  // ======================= layer 2: 64 sentence steps =======================
  __syncthreads();   // all wih1 reads done before overwrite
  for (int q = 0; q < 64; ++q) {
    const int idx = (q << 9) + tid;
    const int rr = idx >> 10, col = idx & 1023;
    wih_lds[idx] = Wih2[(size_t)(((rr >> 3) << 10) + u0 + (rr & 7)) * 1024 + col];
  }
#pragma unroll
  for (int g = 0; g < 4; ++g) {
    const int grow = (g << 10) + u0 + wv;
    bias[g] = bih2[grow] + bhh2[grow];
    const float* ph = Whh2 + (size_t)grow * 1024 + l;
#pragma unroll
    for (int m = 0; m < 16; ++m) whh[g][m] = ph[m << 6];
  }
#pragma unroll
  for (int g = 0; g < 4; ++g)
#pragma unroll
    for (int m = 0; m < 16; ++m) asm volatile("" : "+v"(whh[g][m]));
  c = c2_0[u0 + wv];

  for (int s2 = 0; s2 < SS; ++s2) {
    const unsigned kg = (unsigned)(T1 + s2);
    const int p = (int)(kg & 1), pe = s2 & 1;
    {   // enc row: fp32-tagged pairs; tags ancient -> first try
      const u64* q = encs64 + ((size_t)s2 << 10) + (tid << 1);
      const unsigned t = (unsigned)(s2 + 1);
      u32x4 r;
      for (;;) { r = load16_sc1(q);
        if (__builtin_expect(r.y == t && r.w == t, 1)) break; }
      e_lds[pe][(tid << 1) + 0] = __uint_as_float(r.x);
      e_lds[pe][(tid << 1) + 1] = __uint_as_float(r.z);
    }
    // h gate; s2==0 spins for tag 8192 (boundary), then overrides with h2_0
    if (tid < 256) {
      const u64* q = hbuf64 + ((size_t)p << 9) + (tid << 1);
      u32x4 r;
      for (;;) { r = load16_sc1(q);
        if (__builtin_expect(r.y == kg && r.w == kg, 1)) break; }
      const float2 ha = upk2(r.x), hb = upk2(r.z);
      float* d = h_lds[p] + (tid << 2);
      d[0] = ha.x; d[1] = ha.y; d[2] = hb.x; d[3] = hb.y;
    }
    if (s2 == 0) {
      h_lds[0][(tid << 1) + 0] = h2_0[(tid << 1) + 0];
      h_lds[0][(tid << 1) + 1] = h2_0[(tid << 1) + 1];
    }
    __syncthreads();   // B1

    float a0 = 0.f, a1 = 0.f, a2 = 0.f, a3 = 0.f;
#pragma unroll
    for (int m = 0; m < 16; ++m) {
      const int cix = (m << 6) + l;
      const float ev = e_lds[pe][cix];
      a0 += wih_lds[rb0 + cix] * ev; a1 += wih_lds[rb1 + cix] * ev;
      a2 += wih_lds[rb2 + cix] * ev; a3 += wih_lds[rb3 + cix] * ev;
      const float hv = h_lds[p][cix];
      a0 += whh[0][m] * hv; a1 += whh[1][m] * hv;
      a2 += whh[2][m] * hv; a3 += whh[3][m] * hv;
    }
#pragma unroll
    for (int mm = 1; mm < 64; mm <<= 1) {
      a0 += __shfl_xor(a0, mm); a1 += __shfl_xor(a1, mm);
      a2 += __shfl_xor(a2, mm); a3 += __shfl_xor(a3, mm);
    }
    const float ig = a0 + bias[0], fg = a1 + bias[1];
    const float gg = a2 + bias[2], og = a3 + bias[3];
    const float si = 1.f / (1.f + __expf(-ig));
    const float sf = 1.f / (1.f + __expf(-fg));
    const float so = 1.f / (1.f + __expf(-og));
    c = sf * c + si * ftanh(gg);
    const float h = so * ftanh(c);
    if (l == 0) h_out[wv] = h;
    __syncthreads();   // B2
    if (tid < 4)
      aswap(&hbuf64[((size_t)((kg + 1) & 1) << 9) + (wid << 2) + tid],
            ((u64)(kg + 1u) << 32) |
            (u64)pk2(h_out[(tid << 1)], h_out[(tid << 1) + 1]));
    row += as_lds[s2] * h;                           // row = asn @ hs2 (online)
  }

  // =================== final projection + sigmoid ===================
  if (l == 0) fin_lds[wv] = row * Wf[u0 + wv];
  __syncthreads();
  if (tid == 0) {
    float pp = 0.f;
#pragma unroll
    for (int j = 0; j < 8; ++j) pp += fin_lds[j];
    aswap(&part64[wid], packf(pp, 1u));
  }
  if (wid == 0) {
    if (tid < NWG) {
      u64 a;
      for (;;) { a = aload(&part64[tid]); if ((unsigned)(a >> 32) == 1u) break; }
      e_lds[0][tid] = __uint_as_float((unsigned)a);
    }
    __syncthreads();
    if (wv == 0) {
      float pp = e_lds[0][l] + e_lds[0][64 + l];
#pragma unroll
      for (int mm = 1; mm < 64; mm <<= 1) pp += __shfl_xor(pp, mm);
      if (l == 0) out[0] = 1.f / (1.f + __expf(-(pp + bfb[0])));
    }
  }
}

extern "C" void kernel_launch(void* const* d_in, const int* in_sizes, int n_in,
                              void* d_out, int out_size, void* d_ws, size_t ws_size,
                              hipStream_t stream) {
  (void)in_sizes; (void)n_in; (void)out_size; (void)ws_size;
  const float* xin  = (const float*)d_in[0];
  const float* h1   = (const float*)d_in[1];
  const float* c1   = (const float*)d_in[2];
  const float* h2   = (const float*)d_in[3];
  const float* c2   = (const float*)d_in[4];
  const float* Wih1 = (const float*)d_in[5];
  const float* Whh1 = (const float*)d_in[6];
  const float* bih1 = (const float*)d_in[7];
  const float* bhh1 = (const float*)d_in[8];
  const float* Wih2 = (const float*)d_in[9];
  const float* Whh2 = (const float*)d_in[10];
  const float* bih2 = (const float*)d_in[11];
  const float* bhh2 = (const float*)d_in[12];
  const float* attw = (const float*)d_in[13];
  const float* atts = (const float*)d_in[14];
  const float* Wf   = (const float*)d_in[15];
  const float* bfb  = (const float*)d_in[16];

  u64* hbuf64 = (u64*)d_ws;                 // 1024 u64 (2 x 512, fp16-packed)
  u64* encs64 = hbuf64 + 1024;              // 65536 u64
  u64* part64 = encs64 + 65536;             // 128 u64
  float* out  = (float*)d_out;

  // tags must start invalid (0) every call — replay-safe, graph-capture legal
  hipMemsetAsync(d_ws, 0, (1024 + 65536 + 128) * sizeof(u64), stream);
  lstm_hier_attn<<<dim3(NWG), dim3(NTH), 0, stream>>>(
      xin, h1, c1, h2, c2, Wih1, Whh1, bih1, bhh1,
      Wih2, Whh2, bih2, bhh2, attw, atts, Wf, bfb,
      hbuf64, encs64, part64, out);
}